// Round 1
// baseline (291.792 us; speedup 1.0000x reference)
//
#include <hip/hip_runtime.h>

// ---------------------------------------------------------------------------
// TransNetSweepingExplRhs: analytic reduction of the reference.
//   h   = x @ W_in^T + b_in ; th = tanh(h); r1u = h + 0.1 b1
//   S_i = 11 I + 0.01 W_i^T W_i  (condition ~1.001 -> 1-term Neumann inverse)
//   b1v = 11 th + 0.1 (r1u @ W1);  y1v = (b1v - (0.01/11)(b1v@W1^T@W1))/11
//   y1u = r1u - 0.1 (y1v @ W1^T);  r2u = y1u + 0.1 b2
//   b2v = 10 th + y1v + 0.1 (r2u @ W2); y2v = Neumann(W2, b2v)
//   y2u = r2u - 0.1 (y2v @ W2^T)
//   out = softmax(y2u @ W_out^T + b_out)
// All GEMMs are bf16 MFMA (fp32 accum), NT layout (B stored [N][K]).
// ---------------------------------------------------------------------------

typedef short bf16x8 __attribute__((ext_vector_type(8)));
typedef float f32x4 __attribute__((ext_vector_type(4)));

__device__ inline unsigned short f2b(float f) {
  union { float f; unsigned int u; } v; v.f = f;
  unsigned int u = v.u;
  return (unsigned short)((u + 0x7FFFu + ((u >> 16) & 1u)) >> 16);
}

__device__ inline void gload16(const void* g, void* l) {
  __builtin_amdgcn_global_load_lds(
      (const __attribute__((address_space(1))) unsigned int*)g,
      (__attribute__((address_space(3))) unsigned int*)l, 16, 0, 0);
}

// C[m,n] = sum_k A[m,k] * B[n,k]   (A: Mx1024 bf16, B: 1024x1024 bf16)
// tile 128x64, BK=32, 256 threads (4 waves 2x2), double-buffered LDS.
__global__ __launch_bounds__(256) void gemm_nt(
    const unsigned short* __restrict__ A,
    const unsigned short* __restrict__ B,
    int K, int mode,
    const float* __restrict__ bias0, const float* __restrict__ bias1,
    const float* __restrict__ src0, const float* __restrict__ src1,
    float* __restrict__ dstf0, float* __restrict__ dstf1,
    unsigned short* __restrict__ dstbf) {
  __shared__ short As[2][128 * 32];
  __shared__ short Bs[2][64 * 32];

  const int tid = threadIdx.x;
  const int lane = tid & 63;
  const int wid = tid >> 6;
  const int wr = wid >> 1;   // wave row 0..1 (64 rows each)
  const int wc = wid & 1;    // wave col 0..1 (32 cols each)
  const int m0 = blockIdx.x * 128;
  const int n0 = blockIdx.y * 64;

  const int l15 = lane & 15;
  const int kb = lane >> 4;      // 0..3
  const int koff = kb * 8;

  const int rowin = lane >> 2;       // 0..15 within chunk
  const int colw = (lane & 3) * 8;   // k-offset for staging

  f32x4 acc[4][2];
#pragma unroll
  for (int f = 0; f < 4; ++f)
#pragma unroll
    for (int g = 0; g < 2; ++g) acc[f][g] = (f32x4){0.f, 0.f, 0.f, 0.f};

  const size_t aBase = (size_t)m0 * K;
  const size_t bBase = (size_t)n0 * K;
  const int nkt = K >> 5;

  // prologue: stage k-tile 0 into buffer 0
  {
    const unsigned short* Ab = A + aBase;
    const unsigned short* Bb = B + bBase;
#pragma unroll
    for (int j = 0; j < 2; ++j) {
      int c = wid * 2 + j;
      int e = c * 512 + lane * 8;
      int row = c * 16 + rowin;
      gload16(Ab + (size_t)row * K + colw, &As[0][e]);
    }
    int e = wid * 512 + lane * 8;
    int row = wid * 16 + rowin;
    gload16(Bb + (size_t)row * K + colw, &Bs[0][e]);
  }
  __syncthreads();

  int cur = 0;
  for (int kt = 0; kt < nkt; ++kt) {
    if (kt + 1 < nkt) {  // prefetch next tile into other buffer
      const unsigned short* Ab = A + aBase + (kt + 1) * 32;
      const unsigned short* Bb = B + bBase + (kt + 1) * 32;
#pragma unroll
      for (int j = 0; j < 2; ++j) {
        int c = wid * 2 + j;
        int e = c * 512 + lane * 8;
        int row = c * 16 + rowin;
        gload16(Ab + (size_t)row * K + colw, &As[cur ^ 1][e]);
      }
      int e = wid * 512 + lane * 8;
      int row = wid * 16 + rowin;
      gload16(Bb + (size_t)row * K + colw, &Bs[cur ^ 1][e]);
    }
    // compute current buffer
    bf16x8 av[4], bv[2];
#pragma unroll
    for (int f = 0; f < 4; ++f) {
      int r = wr * 64 + f * 16 + l15;
      av[f] = *reinterpret_cast<const bf16x8*>(&As[cur][r * 32 + koff]);
    }
#pragma unroll
    for (int g = 0; g < 2; ++g) {
      int r = wc * 32 + g * 16 + l15;
      bv[g] = *reinterpret_cast<const bf16x8*>(&Bs[cur][r * 32 + koff]);
    }
#pragma unroll
    for (int f = 0; f < 4; ++f)
#pragma unroll
      for (int g = 0; g < 2; ++g)
        acc[f][g] = __builtin_amdgcn_mfma_f32_16x16x32_bf16(av[f], bv[g], acc[f][g], 0, 0, 0);
    __syncthreads();
    cur ^= 1;
  }

  // epilogue: C/D layout col=lane&15, row=(lane>>4)*4+j
  const int ldc = 1024;
#pragma unroll
  for (int f = 0; f < 4; ++f) {
#pragma unroll
    for (int g = 0; g < 2; ++g) {
#pragma unroll
      for (int j = 0; j < 4; ++j) {
        int m = m0 + wr * 64 + f * 16 + kb * 4 + j;
        int n = n0 + wc * 32 + g * 16 + l15;
        size_t idx = (size_t)m * ldc + n;
        float v = acc[f][g][j];
        if (mode == 0) {                 // raw bf16 (p = b_v @ W^T)
          dstbf[idx] = f2b(v);
        } else if (mode == 1) {          // h-stage: v = x@Win^T
          float t = v + bias0[n];        // h
          float thv = tanhf(t);
          float r = t + 0.1f * bias1[n]; // r1u
          dstf0[idx] = r;
          dstf1[idx] = thv;
          dstbf[idx] = f2b(r);
        } else if (mode == 2) {          // b1v = 11 th + 0.1 c1
          float b = 11.0f * src0[idx] + 0.1f * v;
          dstf0[idx] = b;
          dstbf[idx] = f2b(b);
        } else if (mode == 3) {          // y_v = b/11 - (0.01/121) s
          float y = (1.0f / 11.0f) * src0[idx] - (0.01f / 121.0f) * v;
          dstf0[idx] = y;
          dstbf[idx] = f2b(y);
        } else if (mode == 4) {          // r2u = r1u - 0.1 d1 + 0.1 b2
          float r = src0[idx] - 0.1f * v + 0.1f * bias0[n];
          dstf0[idx] = r;
          dstbf[idx] = f2b(r);
        } else if (mode == 5) {          // b2v = 10 th + y1v + 0.1 c2
          float b = 10.0f * src0[idx] + src1[idx] + 0.1f * v;
          dstf0[idx] = b;
          dstbf[idx] = f2b(b);
        } else if (mode == 7) {          // y2u = r2u - 0.1 d2
          dstbf[idx] = f2b(src0[idx] - 0.1f * v);
        } else {                         // mode 8: logits = v + b_out
          dstf0[idx] = v + bias0[n];
        }
      }
    }
  }
}

__global__ __launch_bounds__(256) void k_f2bk(const float* __restrict__ s,
                                              unsigned short* __restrict__ d, int n) {
  int i = blockIdx.x * 256 + threadIdx.x;
  if (i < n) d[i] = f2b(s[i]);
}

// convert 1024x1024 f32 -> bf16, plain and transposed
__global__ __launch_bounds__(256) void k_conv_trans(const float* __restrict__ W,
                                                    unsigned short* __restrict__ Wb,
                                                    unsigned short* __restrict__ WTb) {
  __shared__ float tile[32][33];
  const int bx = blockIdx.x * 32;
  const int by = blockIdx.y * 32;
  const int tx = threadIdx.x & 31;
  const int ty = threadIdx.x >> 5;
#pragma unroll
  for (int i = ty; i < 32; i += 8) {
    float v = W[(size_t)(by + i) * 1024 + bx + tx];
    tile[i][tx] = v;
    Wb[(size_t)(by + i) * 1024 + bx + tx] = f2b(v);
  }
  __syncthreads();
#pragma unroll
  for (int i = ty; i < 32; i += 8)
    WTb[(size_t)(bx + i) * 1024 + by + tx] = f2b(tile[tx][i]);
}

// W_out (1000x1024) -> bf16 padded to 1024x1024 (zero rows >= 1000)
__global__ __launch_bounds__(256) void k_pad_wout(const float* __restrict__ W,
                                                  unsigned short* __restrict__ D) {
  int i = blockIdx.x * 256 + threadIdx.x;
  if (i < 1024 * 1024) {
    int r = i >> 10;
    D[i] = (r < 1000) ? f2b(W[i]) : (unsigned short)0;
  }
}

__global__ __launch_bounds__(256) void k_pad_bout(const float* __restrict__ b,
                                                  float* __restrict__ d) {
  int i = blockIdx.x * 256 + threadIdx.x;
  if (i < 1024) d[i] = (i < 1000) ? b[i] : 0.0f;
}

// row softmax over first 1000 cols of 2048x1024 logits -> 2048x1000 out
__global__ __launch_bounds__(256) void k_softmax(const float* __restrict__ lg,
                                                 float* __restrict__ out) {
  const int r = blockIdx.x;
  const float* p = lg + (size_t)r * 1024;
  float* q = out + (size_t)r * 1000;
  const int tid = threadIdx.x;
  const int lane = tid & 63;
  const int w = tid >> 6;
  __shared__ float redm[4];
  __shared__ float reds[4];
  float m = -3.0e38f;
  for (int i = tid; i < 1000; i += 256) m = fmaxf(m, p[i]);
#pragma unroll
  for (int o = 32; o > 0; o >>= 1) m = fmaxf(m, __shfl_xor(m, o));
  if (lane == 0) redm[w] = m;
  __syncthreads();
  m = fmaxf(fmaxf(redm[0], redm[1]), fmaxf(redm[2], redm[3]));
  float s = 0.0f;
  for (int i = tid; i < 1000; i += 256) {
    float e = __expf(p[i] - m);
    q[i] = e;
    s += e;
  }
#pragma unroll
  for (int o = 32; o > 0; o >>= 1) s += __shfl_xor(s, o);
  if (lane == 0) reds[w] = s;
  __syncthreads();
  float inv = 1.0f / (reds[0] + reds[1] + reds[2] + reds[3]);
  for (int i = tid; i < 1000; i += 256) q[i] *= inv;
}

extern "C" void kernel_launch(void* const* d_in, const int* in_sizes, int n_in,
                              void* d_out, int out_size, void* d_ws, size_t ws_size,
                              hipStream_t stream) {
  const float* x = (const float*)d_in[0];
  const float* W_in = (const float*)d_in[1];
  const float* b_in = (const float*)d_in[2];
  const float* W1 = (const float*)d_in[3];
  const float* b1 = (const float*)d_in[4];
  const float* W2 = (const float*)d_in[5];
  const float* b2 = (const float*)d_in[6];
  const float* W_out = (const float*)d_in[7];
  const float* b_out = (const float*)d_in[8];
  float* out = (float*)d_out;

  const size_t Bm = 2048, U = 1024;
  char* ws = (char*)d_ws;
  size_t off = 0;
  auto alloc = [&](size_t bytes) -> void* {
    void* p = ws + off;
    off += (bytes + 255) & ~(size_t)255;
    return p;
  };
  unsigned short* xb = (unsigned short*)alloc(Bm * U * 2);
  unsigned short* winb = (unsigned short*)alloc(U * U * 2);
  unsigned short* w1b = (unsigned short*)alloc(U * U * 2);
  unsigned short* w1tb = (unsigned short*)alloc(U * U * 2);
  unsigned short* w2b = (unsigned short*)alloc(U * U * 2);
  unsigned short* w2tb = (unsigned short*)alloc(U * U * 2);
  unsigned short* woutb = (unsigned short*)alloc(U * U * 2);
  float* boutp = (float*)alloc(U * 4);
  float* r1u = (float*)alloc(Bm * U * 4);
  float* th = (float*)alloc(Bm * U * 4);
  float* bv = (float*)alloc(Bm * U * 4);   // b1v then b2v
  float* y1v = (float*)alloc(Bm * U * 4);  // y1v then y2v (unused)
  float* r2u = (float*)alloc(Bm * U * 4);
  float* lgts = (float*)alloc(Bm * U * 4);
  unsigned short* bfA0 = (unsigned short*)alloc(Bm * U * 2);
  unsigned short* bfA1 = (unsigned short*)alloc(Bm * U * 2);

  // prep
  k_f2bk<<<(int)((Bm * U) / 256), 256, 0, stream>>>(x, xb, (int)(Bm * U));
  k_f2bk<<<(int)((U * U) / 256), 256, 0, stream>>>(W_in, winb, (int)(U * U));
  dim3 tg(32, 32);
  k_conv_trans<<<tg, 256, 0, stream>>>(W1, w1b, w1tb);
  k_conv_trans<<<tg, 256, 0, stream>>>(W2, w2b, w2tb);
  k_pad_wout<<<(int)((U * U) / 256), 256, 0, stream>>>(W_out, woutb);
  k_pad_bout<<<4, 256, 0, stream>>>(b_out, boutp);

  dim3 gg(16, 16);  // (M/128, N/64)
  // G0: h-stage
  gemm_nt<<<gg, 256, 0, stream>>>(xb, winb, 1024, 1, b_in, b1, nullptr, nullptr, r1u, th, bfA0);
  // G1: c1 = r1u @ W1  -> b1v
  gemm_nt<<<gg, 256, 0, stream>>>(bfA0, w1tb, 1024, 2, nullptr, nullptr, th, nullptr, bv, nullptr, bfA1);
  // G2: p1 = b1v @ W1^T
  gemm_nt<<<gg, 256, 0, stream>>>(bfA1, w1b, 1024, 0, nullptr, nullptr, nullptr, nullptr, nullptr, nullptr, bfA0);
  // G3: s1 = p1 @ W1 -> y1v
  gemm_nt<<<gg, 256, 0, stream>>>(bfA0, w1tb, 1024, 3, nullptr, nullptr, bv, nullptr, y1v, nullptr, bfA1);
  // G4: d1 = y1v @ W1^T -> r2u
  gemm_nt<<<gg, 256, 0, stream>>>(bfA1, w1b, 1024, 4, b2, nullptr, r1u, nullptr, r2u, nullptr, bfA0);
  // G5: c2 = r2u @ W2 -> b2v
  gemm_nt<<<gg, 256, 0, stream>>>(bfA0, w2tb, 1024, 5, nullptr, nullptr, th, y1v, bv, nullptr, bfA1);
  // G6: p2 = b2v @ W2^T
  gemm_nt<<<gg, 256, 0, stream>>>(bfA1, w2b, 1024, 0, nullptr, nullptr, nullptr, nullptr, nullptr, nullptr, bfA0);
  // G7: s2 = p2 @ W2 -> y2v
  gemm_nt<<<gg, 256, 0, stream>>>(bfA0, w2tb, 1024, 3, nullptr, nullptr, bv, nullptr, y1v, nullptr, bfA1);
  // G8: d2 = y2v @ W2^T -> y2u (bf16 only)
  gemm_nt<<<gg, 256, 0, stream>>>(bfA1, w2b, 1024, 7, nullptr, nullptr, r2u, nullptr, nullptr, nullptr, bfA0);
  // G9: logits = y2u @ Wout^T + bout
  gemm_nt<<<gg, 256, 0, stream>>>(bfA0, woutb, 1024, 8, boutp, nullptr, nullptr, nullptr, lgts, nullptr, nullptr);

  k_softmax<<<2048, 256, 0, stream>>>(lgts, out);
}

// Round 2
// 222.161 us; speedup vs baseline: 1.3134x; 1.3134x over previous
//
#include <hip/hip_runtime.h>

// ---------------------------------------------------------------------------
// TransNetSweepingExplRhs — analytic reduction:
//   h = x@W_in^T + b_in ; th = tanh(h); r1u = h + 0.1 b1
//   Q_i = I/11 - (0.01/121) W_i^T W_i   (1-term Neumann inverse of
//         S_i = 11 I + 0.01 W_i^T W_i; ||0.01 P/11|| ~ 1.2e-3 -> trunc 1.5e-6)
//   b1v = 11 th + 0.1 (r1u@W1); y1v = b1v@Q1; r2u = r1u - 0.1 (y1v@W1^T) + 0.1 b2
//   b2v = 10 th + y1v + 0.1 (r2u@W2); y2v = b2v@Q2; y2u = r2u - 0.1 (y2v@W2^T)
//   out = softmax(y2u@W_out^T + b_out)
// 8 sequential 2048x1024x1024 GEMMs + 1 z-batched 1024^3 pair (Q1,Q2).
// GEMM: bf16 MFMA 16x16x32, tile 64x64 BK=32, 256 thr, grid 512 = 2 blocks/CU.
// ---------------------------------------------------------------------------

typedef short bf16x8 __attribute__((ext_vector_type(8)));
typedef float f32x4 __attribute__((ext_vector_type(4)));

__device__ inline unsigned short f2b(float f) {
  union { float f; unsigned int u; } v; v.f = f;
  unsigned int u = v.u;
  return (unsigned short)((u + 0x7FFFu + ((u >> 16) & 1u)) >> 16);
}

__device__ inline void gload16(const void* g, void* l) {
  __builtin_amdgcn_global_load_lds(
      (const __attribute__((address_space(1))) unsigned int*)g,
      (__attribute__((address_space(3))) unsigned int*)l, 16, 0, 0);
}

// C[m,n] = sum_k A[m,k]*B[n,k], K=1024 fixed, ldc=1024.
// tile 64x64, BK=32, 256 threads (4 waves 2x2, wave tile 32x32), dbuf LDS.
__global__ __launch_bounds__(256) void gemm_nt(
    const unsigned short* __restrict__ A,
    const unsigned short* __restrict__ B,
    int mode, size_t zstr,
    const float* __restrict__ bias0, const float* __restrict__ bias1,
    const float* __restrict__ src0, const float* __restrict__ src1,
    float* __restrict__ dstf0, float* __restrict__ dstf1,
    unsigned short* __restrict__ dstbf) {
  constexpr int K = 1024;
  __shared__ short As[2][64 * 32];
  __shared__ short Bs[2][64 * 32];

  const size_t zoff = (size_t)blockIdx.z * zstr;
  A += zoff;
  B += zoff;
  dstbf += zoff;  // only dereferenced when mode writes bf16 (z>0 only for QG)

  const int tid = threadIdx.x;
  const int lane = tid & 63;
  const int wid = tid >> 6;
  const int wr = wid >> 1;  // wave row 0..1 (32 rows each)
  const int wc = wid & 1;   // wave col 0..1 (32 cols each)
  const int m0 = blockIdx.x * 64;
  const int n0 = blockIdx.y * 64;

  const int l15 = lane & 15;
  const int kb = lane >> 4;  // 0..3
  const int koff = kb * 8;

  const int srow = tid >> 2;        // 0..63
  const int scol = (tid & 3) * 8;   // k-offset for staging

  f32x4 acc[2][2];
#pragma unroll
  for (int f = 0; f < 2; ++f)
#pragma unroll
    for (int g = 0; g < 2; ++g) acc[f][g] = (f32x4){0.f, 0.f, 0.f, 0.f};

  const unsigned short* Ab = A + (size_t)(m0 + srow) * K + scol;
  const unsigned short* Bb = B + (size_t)(n0 + srow) * K + scol;

  // prologue: stage k-tile 0 into buffer 0 (one 16B gload per thread per mat)
  gload16(Ab, &As[0][tid * 8]);
  gload16(Bb, &Bs[0][tid * 8]);
  __syncthreads();

  int cur = 0;
  for (int kt = 0; kt < 32; ++kt) {
    if (kt < 31) {  // prefetch next k-tile into other buffer
      gload16(Ab + (kt + 1) * 32, &As[cur ^ 1][tid * 8]);
      gload16(Bb + (kt + 1) * 32, &Bs[cur ^ 1][tid * 8]);
    }
    bf16x8 av[2], bv[2];
#pragma unroll
    for (int f = 0; f < 2; ++f)
      av[f] = *reinterpret_cast<const bf16x8*>(&As[cur][(wr * 32 + f * 16 + l15) * 32 + koff]);
#pragma unroll
    for (int g = 0; g < 2; ++g)
      bv[g] = *reinterpret_cast<const bf16x8*>(&Bs[cur][(wc * 32 + g * 16 + l15) * 32 + koff]);
#pragma unroll
    for (int f = 0; f < 2; ++f)
#pragma unroll
      for (int g = 0; g < 2; ++g)
        acc[f][g] = __builtin_amdgcn_mfma_f32_16x16x32_bf16(av[f], bv[g], acc[f][g], 0, 0, 0);
    __syncthreads();
    cur ^= 1;
  }

  // epilogue: C/D layout col = lane&15, row = (lane>>4)*4 + j
#pragma unroll
  for (int f = 0; f < 2; ++f) {
#pragma unroll
    for (int g = 0; g < 2; ++g) {
#pragma unroll
      for (int j = 0; j < 4; ++j) {
        int m = m0 + wr * 32 + f * 16 + kb * 4 + j;
        int n = n0 + wc * 32 + g * 16 + l15;
        size_t idx = (size_t)m * 1024 + n;
        float v = acc[f][g][j];
        if (mode == 0) {                  // y2v: raw bf16
          dstbf[idx] = f2b(v);
        } else if (mode == 1) {           // h-stage: v = x@Win^T
          float h = v + bias0[n];
          float thv = tanhf(h);
          float r = h + 0.1f * bias1[n];  // r1u
          dstf0[idx] = r;
          dstf1[idx] = thv;
          dstbf[idx] = f2b(r);
        } else if (mode == 2) {           // b1v = 11 th + 0.1 c1
          dstbf[idx] = f2b(11.0f * src0[idx] + 0.1f * v);
        } else if (mode == 3) {           // y1v = b1v@Q1 : keep f32 + bf16
          dstf0[idx] = v;
          dstbf[idx] = f2b(v);
        } else if (mode == 4) {           // r2u = r1u - 0.1 d1 + 0.1 b2
          float r = src0[idx] - 0.1f * v + 0.1f * bias0[n];
          dstf0[idx] = r;
          dstbf[idx] = f2b(r);
        } else if (mode == 5) {           // b2v = 10 th + y1v + 0.1 c2
          dstbf[idx] = f2b(10.0f * src0[idx] + src1[idx] + 0.1f * v);
        } else if (mode == 7) {           // y2u = r2u - 0.1 d2
          dstbf[idx] = f2b(src0[idx] - 0.1f * v);
        } else if (mode == 8) {           // logits = v + b_out
          dstf0[idx] = v + bias0[n];
        } else {                          // mode 9: Q = I/11 - (0.01/121) P
          float q = (m == n ? (1.0f / 11.0f) : 0.0f) - (0.01f / 121.0f) * v;
          dstbf[idx] = f2b(q);
        }
      }
    }
  }
}

// flat prep: x->bf16, W_in->bf16, W_out->bf16 padded 1024x1024, b_out padded
__global__ __launch_bounds__(256) void k_prep(
    const float* __restrict__ x, const float* __restrict__ Win,
    const float* __restrict__ Wout, const float* __restrict__ bout,
    unsigned short* __restrict__ xb, unsigned short* __restrict__ winb,
    unsigned short* __restrict__ woutb, float* __restrict__ boutp) {
  const int N1 = 2048 * 1024;
  const int N2 = N1 + 1024 * 1024;
  const int N3 = N2 + 1024 * 1024;
  int i = blockIdx.x * 256 + threadIdx.x;
  if (i < N1) {
    xb[i] = f2b(x[i]);
  } else if (i < N2) {
    int j = i - N1;
    winb[j] = f2b(Win[j]);
  } else if (i < N3) {
    int j = i - N2;
    woutb[j] = ((j >> 10) < 1000) ? f2b(Wout[j]) : (unsigned short)0;
  } else {
    int j = i - N3;
    if (j < 1024) boutp[j] = (j < 1000) ? bout[j] : 0.0f;
  }
}

// z-batched: W{1,2} (1024x1024 f32) -> bf16 plain (Wb) and transposed (WTb)
__global__ __launch_bounds__(256) void k_conv_trans(
    const float* __restrict__ W1, const float* __restrict__ W2,
    unsigned short* __restrict__ Wb, unsigned short* __restrict__ WTb) {
  const float* W = blockIdx.z ? W2 : W1;
  const size_t zo = (size_t)blockIdx.z << 20;
  Wb += zo;
  WTb += zo;
  __shared__ float tile[32][33];
  const int bx = blockIdx.x * 32;
  const int by = blockIdx.y * 32;
  const int tx = threadIdx.x & 31;
  const int ty = threadIdx.x >> 5;
#pragma unroll
  for (int i = ty; i < 32; i += 8) {
    float v = W[(size_t)(by + i) * 1024 + bx + tx];
    tile[i][tx] = v;
    Wb[(size_t)(by + i) * 1024 + bx + tx] = f2b(v);
  }
  __syncthreads();
#pragma unroll
  for (int i = ty; i < 32; i += 8)
    WTb[(size_t)(bx + i) * 1024 + by + tx] = f2b(tile[tx][i]);
}

// row softmax over first 1000 cols of 2048x1024 logits -> 2048x1000
__global__ __launch_bounds__(256) void k_softmax(const float* __restrict__ lg,
                                                 float* __restrict__ out) {
  const int r = blockIdx.x;
  const float* p = lg + (size_t)r * 1024;
  float* q = out + (size_t)r * 1000;
  const int tid = threadIdx.x;
  const int lane = tid & 63;
  const int w = tid >> 6;
  __shared__ float redm[4];
  __shared__ float reds[4];
  float m = -3.0e38f;
  for (int i = tid; i < 1000; i += 256) m = fmaxf(m, p[i]);
#pragma unroll
  for (int o = 32; o > 0; o >>= 1) m = fmaxf(m, __shfl_xor(m, o));
  if (lane == 0) redm[w] = m;
  __syncthreads();
  m = fmaxf(fmaxf(redm[0], redm[1]), fmaxf(redm[2], redm[3]));
  float s = 0.0f;
  for (int i = tid; i < 1000; i += 256) {
    float e = __expf(p[i] - m);
    q[i] = e;
    s += e;
  }
#pragma unroll
  for (int o = 32; o > 0; o >>= 1) s += __shfl_xor(s, o);
  if (lane == 0) reds[w] = s;
  __syncthreads();
  float inv = 1.0f / (reds[0] + reds[1] + reds[2] + reds[3]);
  for (int i = tid; i < 1000; i += 256) q[i] *= inv;
}

extern "C" void kernel_launch(void* const* d_in, const int* in_sizes, int n_in,
                              void* d_out, int out_size, void* d_ws, size_t ws_size,
                              hipStream_t stream) {
  const float* x = (const float*)d_in[0];
  const float* W_in = (const float*)d_in[1];
  const float* b_in = (const float*)d_in[2];
  const float* W1 = (const float*)d_in[3];
  const float* b1 = (const float*)d_in[4];
  const float* W2 = (const float*)d_in[5];
  const float* b2 = (const float*)d_in[6];
  const float* W_out = (const float*)d_in[7];
  const float* b_out = (const float*)d_in[8];
  float* out = (float*)d_out;

  const size_t Bm = 2048, U = 1024, M1 = U * U;
  char* ws = (char*)d_ws;
  size_t off = 0;
  auto alloc = [&](size_t bytes) -> void* {
    void* p = ws + off;
    off += (bytes + 255) & ~(size_t)255;
    return p;
  };
  unsigned short* xb = (unsigned short*)alloc(Bm * U * 2);
  unsigned short* winb = (unsigned short*)alloc(M1 * 2);
  unsigned short* wb = (unsigned short*)alloc(2 * M1 * 2);   // w1b, w2b
  unsigned short* wtb = (unsigned short*)alloc(2 * M1 * 2);  // w1tb, w2tb
  unsigned short* qb = (unsigned short*)alloc(2 * M1 * 2);   // q1b, q2b
  unsigned short* woutb = (unsigned short*)alloc(M1 * 2);
  float* boutp = (float*)alloc(U * 4);
  float* r1u = (float*)alloc(Bm * U * 4);
  float* th = (float*)alloc(Bm * U * 4);
  float* y1v = (float*)alloc(Bm * U * 4);
  float* r2u = (float*)alloc(Bm * U * 4);
  float* lgts = (float*)alloc(Bm * U * 4);
  unsigned short* bfA0 = (unsigned short*)alloc(Bm * U * 2);
  unsigned short* bfA1 = (unsigned short*)alloc(Bm * U * 2);

  // prep: 2 dispatches
  const int TOT = (int)(Bm * U + M1 + M1 + U);
  k_prep<<<(TOT + 255) / 256, 256, 0, stream>>>(x, W_in, W_out, b_out, xb, winb, woutb, boutp);
  k_conv_trans<<<dim3(32, 32, 2), 256, 0, stream>>>(W1, W2, wb, wtb);

  const size_t ZS = M1;  // z-stride in elements
  // QG (z-batched): Q_i = I/11 - (0.01/121) W_i^T W_i   (A=B=wtb)
  gemm_nt<<<dim3(16, 16, 2), 256, 0, stream>>>(wtb, wtb, 9, ZS, nullptr, nullptr,
                                               nullptr, nullptr, nullptr, nullptr, qb);
  dim3 gg(32, 16, 1);  // 2048/64 x 1024/64 = 512 blocks
  // G0: h-stage
  gemm_nt<<<gg, 256, 0, stream>>>(xb, winb, 1, 0, b_in, b1, nullptr, nullptr, r1u, th, bfA0);
  // G1: c1 = r1u@W1 -> b1v
  gemm_nt<<<gg, 256, 0, stream>>>(bfA0, wtb, 2, 0, nullptr, nullptr, th, nullptr, nullptr, nullptr, bfA1);
  // G2: y1v = b1v@Q1
  gemm_nt<<<gg, 256, 0, stream>>>(bfA1, qb, 3, 0, nullptr, nullptr, nullptr, nullptr, y1v, nullptr, bfA0);
  // G3: d1 = y1v@W1^T -> r2u
  gemm_nt<<<gg, 256, 0, stream>>>(bfA0, wb, 4, 0, b2, nullptr, r1u, nullptr, r2u, nullptr, bfA1);
  // G4: c2 = r2u@W2 -> b2v
  gemm_nt<<<gg, 256, 0, stream>>>(bfA1, wtb + M1, 5, 0, nullptr, nullptr, th, y1v, nullptr, nullptr, bfA0);
  // G5: y2v = b2v@Q2
  gemm_nt<<<gg, 256, 0, stream>>>(bfA0, qb + M1, 0, 0, nullptr, nullptr, nullptr, nullptr, nullptr, nullptr, bfA1);
  // G6: d2 = y2v@W2^T -> y2u
  gemm_nt<<<gg, 256, 0, stream>>>(bfA1, wb + M1, 7, 0, nullptr, nullptr, r2u, nullptr, nullptr, nullptr, bfA0);
  // G7: logits = y2u@Wout^T + bout
  gemm_nt<<<gg, 256, 0, stream>>>(bfA0, woutb, 8, 0, boutp, nullptr, nullptr, nullptr, lgts, nullptr, nullptr);

  k_softmax<<<2048, 256, 0, stream>>>(lgts, out);
}

// Round 4
// 187.876 us; speedup vs baseline: 1.5531x; 1.1825x over previous
//
#include <hip/hip_runtime.h>

// ---------------------------------------------------------------------------
// TransNetSweepingExplRhs — analytic reduction (derivation in R1/R2):
//   h = x@W_in^T + b_in ; th = tanh(h); r1u = h + 0.1 b1
//   Q_i = I/11 - (0.01/121) W_i^T W_i      (1-term Neumann inverse)
//   b1v = 11 th + 0.1 (r1u@W1); y1v = b1v@Q1
//   r2u = r1u - 0.1 (y1v@W1^T) + 0.1 b2
//   b2v = 10 th + y1v + 0.1 (r2u@W2); y2v = b2v@Q2
//   y2u = r2u - 0.1 (y2v@W2^T);  out = softmax(y2u@W_out^T + b_out)
// Multi-dispatch (known-good launch path). This round:
//  * LDS chunk-rotation swizzle  c' = (g + (row>>1))&3  via pre-swizzled
//    global source (gload_lds dest linear) -> 8-way bank conflict -> 2-way(free)
//  * XCD-sharded tile map bx=(b&7)*4+((b>>3)&3), by=b>>5 -> 2.5 MB/XCD L2-res.
//  * QG fused into G0 dispatch; prep in one dispatch. 10 dispatches.
// ---------------------------------------------------------------------------

typedef short bf16x8 __attribute__((ext_vector_type(8)));
typedef float f32x4 __attribute__((ext_vector_type(4)));

#define M1 1048576

__device__ __forceinline__ unsigned short f2b(float f) {
  union { float f; unsigned int u; } v; v.f = f;
  unsigned int u = v.u;
  return (unsigned short)((u + 0x7FFFu + ((u >> 16) & 1u)) >> 16);
}

__device__ __forceinline__ void gload16(const void* g, void* l) {
  __builtin_amdgcn_global_load_lds(
      (const __attribute__((address_space(1))) unsigned int*)g,
      (__attribute__((address_space(3))) unsigned int*)l, 16, 0, 0);
}

// C[m,n] = sum_k A[m,k]*B[n,k], K=1024, tile 64x64 at (bx,by), dbuf LDS,
// swizzled chunk layout: LDS(row r, chunk c') holds global chunk
// g = (c' - (r>>1)) & 3 ; read chunk kb at c' = (kb + (r>>1)) & 3.
__device__ __forceinline__ void gemm64(
    const unsigned short* __restrict__ A, const unsigned short* __restrict__ B,
    int bx, int by, int mode,
    const float* bias0, const float* bias1,
    const float* src0, const float* src1,
    float* dstf0, float* dstf1, unsigned short* dstbf,
    short (*As)[2048], short (*Bs)[2048]) {
  constexpr int K = 1024;
  const int tid = threadIdx.x;
  const int lane = tid & 63;
  const int wid = tid >> 6;
  const int wr = wid >> 1;
  const int wc = wid & 1;
  const int m0 = bx * 64;
  const int n0 = by * 64;
  const int l15 = lane & 15;
  const int kb = lane >> 4;
  const int csw = (l15 >> 1) & 3;              // (row>>1)&3 for fragment rows
  const int coff = (((kb + csw) & 3) << 3);    // swizzled chunk short-offset
  const int srow = tid >> 2;
  const int sg = ((tid & 3) - ((tid >> 3) & 3)) & 3;  // pre-swizzled src chunk

  f32x4 acc[2][2];
#pragma unroll
  for (int f = 0; f < 2; ++f)
#pragma unroll
    for (int g = 0; g < 2; ++g) acc[f][g] = (f32x4){0.f, 0.f, 0.f, 0.f};

  const unsigned short* Ab = A + (size_t)(m0 + srow) * K + sg * 8;
  const unsigned short* Bb = B + (size_t)(n0 + srow) * K + sg * 8;

  gload16(Ab, &As[0][tid * 8]);
  gload16(Bb, &Bs[0][tid * 8]);
  __syncthreads();

  int cur = 0;
  for (int kt = 0; kt < 32; ++kt) {
    if (kt < 31) {
      gload16(Ab + (kt + 1) * 32, &As[cur ^ 1][tid * 8]);
      gload16(Bb + (kt + 1) * 32, &Bs[cur ^ 1][tid * 8]);
    }
    bf16x8 av[2], bv[2];
#pragma unroll
    for (int f = 0; f < 2; ++f)
      av[f] = *reinterpret_cast<const bf16x8*>(
          &As[cur][(wr * 32 + f * 16 + l15) * 32 + coff]);
#pragma unroll
    for (int g = 0; g < 2; ++g)
      bv[g] = *reinterpret_cast<const bf16x8*>(
          &Bs[cur][(wc * 32 + g * 16 + l15) * 32 + coff]);
#pragma unroll
    for (int f = 0; f < 2; ++f)
#pragma unroll
      for (int g = 0; g < 2; ++g)
        acc[f][g] = __builtin_amdgcn_mfma_f32_16x16x32_bf16(av[f], bv[g], acc[f][g], 0, 0, 0);
    __syncthreads();
    cur ^= 1;
  }

  // epilogue: C/D layout col = lane&15, row = (lane>>4)*4 + j
#pragma unroll
  for (int f = 0; f < 2; ++f) {
#pragma unroll
    for (int g = 0; g < 2; ++g) {
#pragma unroll
      for (int j = 0; j < 4; ++j) {
        int m = m0 + wr * 32 + f * 16 + kb * 4 + j;
        int n = n0 + wc * 32 + g * 16 + l15;
        size_t idx = (size_t)m * 1024 + n;
        float v = acc[f][g][j];
        if (mode == 0) {                  // raw bf16
          dstbf[idx] = f2b(v);
        } else if (mode == 1) {           // h-stage
          float h = v + bias0[n];
          float thv = tanhf(h);
          float r = h + 0.1f * bias1[n];
          dstf0[idx] = r;
          dstf1[idx] = thv;
          dstbf[idx] = f2b(r);
        } else if (mode == 2) {           // b1v = 11 th + 0.1 c1
          dstbf[idx] = f2b(11.0f * src0[idx] + 0.1f * v);
        } else if (mode == 3) {           // y1v
          dstf0[idx] = v;
          dstbf[idx] = f2b(v);
        } else if (mode == 4) {           // r2u = r1u - 0.1 d1 + 0.1 b2
          float r = src0[idx] - 0.1f * v + 0.1f * bias0[n];
          dstf0[idx] = r;
          dstbf[idx] = f2b(r);
        } else if (mode == 5) {           // b2v = 10 th + y1v + 0.1 c2
          dstbf[idx] = f2b(10.0f * src0[idx] + src1[idx] + 0.1f * v);
        } else if (mode == 7) {           // y2u = r2u - 0.1 d2
          dstbf[idx] = f2b(src0[idx] - 0.1f * v);
        } else if (mode == 8) {           // logits
          dstf0[idx] = v + bias0[n];
        } else {                          // mode 9: Q = I/11 - (0.01/121) P
          float q = (m == n ? (1.0f / 11.0f) : 0.0f) - (0.01f / 121.0f) * v;
          dstbf[idx] = f2b(q);
        }
      }
    }
  }
}

// main-chain GEMM, 512 blocks, XCD-sharded tile map
__global__ __launch_bounds__(256) void k_gemm(
    const unsigned short* __restrict__ A, const unsigned short* __restrict__ B,
    int mode, const float* bias0, const float* bias1,
    const float* src0, const float* src1,
    float* dstf0, float* dstf1, unsigned short* dstbf) {
  __shared__ short As[2][2048];
  __shared__ short Bs[2][2048];
  const int b = blockIdx.x;
  const int bx = ((b & 7) << 2) | ((b >> 3) & 3);
  const int by = b >> 5;
  gemm64(A, B, bx, by, mode, bias0, bias1, src0, src1, dstf0, dstf1, dstbf, As, Bs);
}

// stage A: G0 (h-stage, blocks 0..511) + QG (Q1,Q2, blocks 512..1023)
__global__ __launch_bounds__(256) void k_stageA(
    const unsigned short* __restrict__ xb, const unsigned short* __restrict__ winb,
    const unsigned short* __restrict__ wtb,
    const float* __restrict__ b_in, const float* __restrict__ b1,
    float* __restrict__ r1u, float* __restrict__ th,
    unsigned short* __restrict__ bfA0, unsigned short* __restrict__ qb) {
  __shared__ short As[2][2048];
  __shared__ short Bs[2][2048];
  const int b = blockIdx.x;
  if (b < 512) {
    const int bx = ((b & 7) << 2) | ((b >> 3) & 3);
    const int by = b >> 5;
    gemm64(xb, winb, bx, by, 1, b_in, b1, nullptr, nullptr, r1u, th, bfA0, As, Bs);
  } else {
    int r = b - 512;
    const int z = r >> 8;
    r &= 255;
    const int qbx = ((r & 7) << 1) | ((r >> 3) & 1);
    const int qby = (r >> 4) & 15;
    const unsigned short* wt = wtb + (size_t)z * M1;
    gemm64(wt, wt, qbx, qby, 9, nullptr, nullptr, nullptr, nullptr,
           nullptr, nullptr, qb + (size_t)z * M1, As, Bs);
  }
}

// one-dispatch prep: W1/W2 bf16+transpose (blocks 0..2047), x (2048..4095),
// W_in (4096..5119), W_out padded (5120..6143), b_out (6144)
__global__ __launch_bounds__(256) void k_prep(
    const float* __restrict__ x, const float* __restrict__ Win,
    const float* __restrict__ W1, const float* __restrict__ W2,
    const float* __restrict__ Wout, const float* __restrict__ bout,
    unsigned short* __restrict__ xb, unsigned short* __restrict__ winb,
    unsigned short* __restrict__ wb, unsigned short* __restrict__ wtb,
    unsigned short* __restrict__ woutb, float* __restrict__ boutp) {
  __shared__ float tile[32][33];
  const int b = blockIdx.x;
  const int tid = threadIdx.x;
  if (b < 2048) {
    const float* W = (b & 1024) ? W2 : W1;
    unsigned short* Wb = wb + ((size_t)(b >> 10) << 20);
    unsigned short* WTb = wtb + ((size_t)(b >> 10) << 20);
    const int rem = b & 1023;
    const int tbx = rem & 31, tby = rem >> 5;
    const int tx = tid & 31, ty = tid >> 5;
#pragma unroll
    for (int i = ty; i < 32; i += 8) {
      float v = W[(size_t)(tby * 32 + i) * 1024 + tbx * 32 + tx];
      tile[i][tx] = v;
      Wb[(size_t)(tby * 32 + i) * 1024 + tbx * 32 + tx] = f2b(v);
    }
    __syncthreads();
#pragma unroll
    for (int i = ty; i < 32; i += 8)
      WTb[(size_t)(tbx * 32 + i) * 1024 + tby * 32 + tx] = f2b(tile[tx][i]);
  } else if (b < 4096) {
    int i = (b - 2048) * 256 + tid;
    float4 v = ((const float4*)x)[i];
    ((ushort4*)xb)[i] = (ushort4){f2b(v.x), f2b(v.y), f2b(v.z), f2b(v.w)};
  } else if (b < 5120) {
    int i = (b - 4096) * 256 + tid;
    float4 v = ((const float4*)Win)[i];
    ((ushort4*)winb)[i] = (ushort4){f2b(v.x), f2b(v.y), f2b(v.z), f2b(v.w)};
  } else if (b < 6144) {
    int i = (b - 5120) * 256 + tid;
    ushort4 o = (ushort4){0, 0, 0, 0};
    if ((i >> 8) < 1000) {
      float4 v = ((const float4*)Wout)[i];
      o = (ushort4){f2b(v.x), f2b(v.y), f2b(v.z), f2b(v.w)};
    }
    ((ushort4*)woutb)[i] = o;
  } else {
    for (int j = tid; j < 1024; j += 256) boutp[j] = (j < 1000) ? bout[j] : 0.0f;
  }
}

// row softmax over first 1000 cols of 2048x1024 logits -> 2048x1000
__global__ __launch_bounds__(256) void k_softmax(const float* __restrict__ lg,
                                                 float* __restrict__ out) {
  const int r = blockIdx.x;
  const float* p = lg + (size_t)r * 1024;
  float* q = out + (size_t)r * 1000;
  const int tid = threadIdx.x;
  const int lane = tid & 63;
  const int w = tid >> 6;
  __shared__ float redm[4];
  __shared__ float reds[4];
  float m = -3.0e38f;
  for (int i = tid; i < 1000; i += 256) m = fmaxf(m, p[i]);
#pragma unroll
  for (int o = 32; o > 0; o >>= 1) m = fmaxf(m, __shfl_xor(m, o));
  if (lane == 0) redm[w] = m;
  __syncthreads();
  m = fmaxf(fmaxf(redm[0], redm[1]), fmaxf(redm[2], redm[3]));
  float s = 0.0f;
  for (int i = tid; i < 1000; i += 256) {
    float e = __expf(p[i] - m);
    q[i] = e;
    s += e;
  }
#pragma unroll
  for (int o = 32; o > 0; o >>= 1) s += __shfl_xor(s, o);
  if (lane == 0) reds[w] = s;
  __syncthreads();
  float inv = 1.0f / (reds[0] + reds[1] + reds[2] + reds[3]);
  for (int i = tid; i < 1000; i += 256) q[i] *= inv;
}

extern "C" void kernel_launch(void* const* d_in, const int* in_sizes, int n_in,
                              void* d_out, int out_size, void* d_ws, size_t ws_size,
                              hipStream_t stream) {
  const float* x = (const float*)d_in[0];
  const float* W_in = (const float*)d_in[1];
  const float* b_in = (const float*)d_in[2];
  const float* W1 = (const float*)d_in[3];
  const float* b1 = (const float*)d_in[4];
  const float* W2 = (const float*)d_in[5];
  const float* b2 = (const float*)d_in[6];
  const float* W_out = (const float*)d_in[7];
  const float* b_out = (const float*)d_in[8];
  float* out = (float*)d_out;

  const size_t Bm = 2048, U = 1024;
  char* ws = (char*)d_ws;
  size_t off = 0;
  auto alloc = [&](size_t bytes) -> void* {
    void* p = ws + off;
    off += (bytes + 255) & ~(size_t)255;
    return p;
  };
  unsigned short* xb = (unsigned short*)alloc(Bm * U * 2);
  unsigned short* winb = (unsigned short*)alloc((size_t)M1 * 2);
  unsigned short* wb = (unsigned short*)alloc(2 * (size_t)M1 * 2);   // W1,W2
  unsigned short* wtb = (unsigned short*)alloc(2 * (size_t)M1 * 2);  // W1^T,W2^T
  unsigned short* qb = (unsigned short*)alloc(2 * (size_t)M1 * 2);   // Q1,Q2
  unsigned short* woutb = (unsigned short*)alloc((size_t)M1 * 2);
  float* boutp = (float*)alloc(U * 4);
  float* r1u = (float*)alloc(Bm * U * 4);
  float* th = (float*)alloc(Bm * U * 4);
  float* y1v = (float*)alloc(Bm * U * 4);
  float* r2u = (float*)alloc(Bm * U * 4);
  float* lgts = (float*)alloc(Bm * U * 4);
  unsigned short* bfA0 = (unsigned short*)alloc(Bm * U * 2);
  unsigned short* bfA1 = (unsigned short*)alloc(Bm * U * 2);

  k_prep<<<6145, 256, 0, stream>>>(x, W_in, W1, W2, W_out, b_out,
                                   xb, winb, wb, wtb, woutb, boutp);
  // stage A: G0 + QG
  k_stageA<<<1024, 256, 0, stream>>>(xb, winb, wtb, b_in, b1, r1u, th, bfA0, qb);
  // G1: c1 = r1u@W1 -> b1v
  k_gemm<<<512, 256, 0, stream>>>(bfA0, wtb, 2, nullptr, nullptr, th, nullptr,
                                  nullptr, nullptr, bfA1);
  // G2: y1v = b1v@Q1
  k_gemm<<<512, 256, 0, stream>>>(bfA1, qb, 3, nullptr, nullptr, nullptr, nullptr,
                                  y1v, nullptr, bfA0);
  // G3: d1 = y1v@W1^T -> r2u
  k_gemm<<<512, 256, 0, stream>>>(bfA0, wb, 4, b2, nullptr, r1u, nullptr,
                                  r2u, nullptr, bfA1);
  // G4: c2 = r2u@W2 -> b2v
  k_gemm<<<512, 256, 0, stream>>>(bfA1, wtb + M1, 5, nullptr, nullptr, th, y1v,
                                  nullptr, nullptr, bfA0);
  // G5: y2v = b2v@Q2
  k_gemm<<<512, 256, 0, stream>>>(bfA0, qb + M1, 0, nullptr, nullptr, nullptr, nullptr,
                                  nullptr, nullptr, bfA1);
  // G6: d2 = y2v@W2^T -> y2u
  k_gemm<<<512, 256, 0, stream>>>(bfA1, wb + M1, 7, nullptr, nullptr, r2u, nullptr,
                                  nullptr, nullptr, bfA0);
  // G7: logits = y2u@Wout^T + bout
  k_gemm<<<512, 256, 0, stream>>>(bfA0, woutb, 8, boutp, nullptr, nullptr, nullptr,
                                  lgts, nullptr, nullptr);

  k_softmax<<<2048, 256, 0, stream>>>(lgts, out);
}